// Round 2
// baseline (1171.656 us; speedup 1.0000x reference)
//
// Round 2: grid-transposed GEMM (B-slab L2/L3 reuse), LDS stride-36 (conflict-free
// b64 frag loads), rmsnorm fused into GEMM A-staging, conv fused into xp kernel,
// 64x128 tile for the skinny out-projection.
#include <hip/hip_runtime.h>

#define D_MODEL 768
#define D_INNER 1536
#define D_XZ    3072
#define D_STATE 16
#define LSEQ    1024
#define NCHUNK  32
#define CLEN    32

typedef float  floatx4 __attribute__((ext_vector_type(4)));
typedef __bf16 bf16x4  __attribute__((ext_vector_type(4)));
typedef __bf16 bf16x8  __attribute__((ext_vector_type(8)));

__device__ __forceinline__ float softplus_f(float x) {
  float e = __expf(-fabsf(x));
  return fmaxf(x, 0.f) + __logf(1.f + e);
}
__device__ __forceinline__ float silu_f(float x) {
  return x / (1.f + __expf(-x));
}

// ---------------- embed gather ----------------
__global__ __launch_bounds__(256) void k_gather(const float* __restrict__ embed,
                                                const int* __restrict__ idx,
                                                float* __restrict__ x) {
  int t = blockIdx.x;
  int tok = idx[t];
  const float* src = embed + (size_t)tok * D_MODEL;
  float* dst = x + (size_t)t * D_MODEL;
  for (int c = threadIdx.x; c < D_MODEL; c += 256) dst[c] = src[c];
}

// ---------------- per-row rmsnorm scale: rs[r] = rsqrt(mean(x^2)+eps) ----------------
__global__ __launch_bounds__(256) void k_rowscale(const float* __restrict__ x,
                                                  float* __restrict__ rs) {
  int lane = threadIdx.x & 63;
  int row = blockIdx.x * 4 + (threadIdx.x >> 6);
  const float* xr = x + (size_t)row * D_MODEL;
  float ss = 0.f;
#pragma unroll
  for (int i = 0; i < 12; i++) { float v = xr[lane + i * 64]; ss += v * v; }
#pragma unroll
  for (int m = 32; m; m >>= 1) ss += __shfl_xor(ss, m, 64);
  if (lane == 0) rs[row] = rsqrtf(ss * (1.f / 768.f) + 1e-5f);
}

// ---------------- NT GEMM: C[m,n] = res?[m,n] + sum_k An[m,k]*B[n,k] ----------------
// An = NORM ? A[m,k]*rs[m]*cw[k] : A[m,k].  A: MxK, B: NxK row-major fp32.
// blockIdx.x = M-tile (consecutive blocks share the B slab -> L2/L3 reuse).
// LDS row stride 36 elems (72 B) -> conflict-free b64 fragment reads.
template <int TM, int TN, bool NORM>
__global__ __launch_bounds__(256) void k_gemm(const float* __restrict__ A,
                                              const float* __restrict__ B,
                                              const float* __restrict__ rs,
                                              const float* __restrict__ cw,
                                              const float* res, float* C,
                                              int M, int N, int K) {
  constexpr int AI = TM / 32, BI = TN / 32;
  constexpr int MT = TM / 32, NT = TN / 32;
  __shared__ __attribute__((aligned(16))) __bf16 As[TM * 36];
  __shared__ __attribute__((aligned(16))) __bf16 Bs[TN * 36];
  const int tid = threadIdx.x;
  const int lane = tid & 63, wave = tid >> 6;
  const int wm = (wave & 1) * (TM / 2), wn = (wave >> 1) * (TN / 2);
  const int fr = lane & 15;
  const int q = lane >> 4;
  const int kq = q * 8;
  const int Mblk = blockIdx.x * TM, Nblk = blockIdx.y * TN;
  const int c4 = (tid & 7) * 4;
  const int r0 = tid >> 3;

  const float* Ab = A + (size_t)(Mblk + r0) * K + c4;
  const float* Bb = B + (size_t)(Nblk + r0) * K + c4;

  floatx4 acc[MT][NT];
#pragma unroll
  for (int i = 0; i < MT; i++)
#pragma unroll
    for (int j = 0; j < NT; j++) {
      floatx4 z = {0.f, 0.f, 0.f, 0.f};
      acc[i][j] = z;
    }

  for (int k0 = 0; k0 < K; k0 += 32) {
    __syncthreads();
    float4 wv4;
    if constexpr (NORM) wv4 = *(const float4*)(cw + k0 + c4);
#pragma unroll
    for (int i = 0; i < AI; i++) {
      float4 va = *(const float4*)(Ab + (size_t)(32 * i) * K + k0);
      if constexpr (NORM) {
        float s = rs[Mblk + r0 + 32 * i];
        va.x *= s * wv4.x; va.y *= s * wv4.y; va.z *= s * wv4.z; va.w *= s * wv4.w;
      }
      bf16x4 ba;
      ba[0] = (__bf16)va.x; ba[1] = (__bf16)va.y; ba[2] = (__bf16)va.z; ba[3] = (__bf16)va.w;
      *(bf16x4*)&As[(r0 + 32 * i) * 36 + c4] = ba;
    }
#pragma unroll
    for (int i = 0; i < BI; i++) {
      float4 vb = *(const float4*)(Bb + (size_t)(32 * i) * K + k0);
      bf16x4 bb;
      bb[0] = (__bf16)vb.x; bb[1] = (__bf16)vb.y; bb[2] = (__bf16)vb.z; bb[3] = (__bf16)vb.w;
      *(bf16x4*)&Bs[(r0 + 32 * i) * 36 + c4] = bb;
    }
    __syncthreads();
    bf16x8 af[MT], bfr[NT];
#pragma unroll
    for (int mt = 0; mt < MT; mt++) {
      int r = wm + mt * 16 + fr;
      bf16x4 lo = *(bf16x4*)&As[r * 36 + kq];
      bf16x4 hi = *(bf16x4*)&As[r * 36 + kq + 4];
      af[mt] = __builtin_shufflevector(lo, hi, 0, 1, 2, 3, 4, 5, 6, 7);
    }
#pragma unroll
    for (int nt = 0; nt < NT; nt++) {
      int r = wn + nt * 16 + fr;
      bf16x4 lo = *(bf16x4*)&Bs[r * 36 + kq];
      bf16x4 hi = *(bf16x4*)&Bs[r * 36 + kq + 4];
      bfr[nt] = __builtin_shufflevector(lo, hi, 0, 1, 2, 3, 4, 5, 6, 7);
    }
#pragma unroll
    for (int mt = 0; mt < MT; mt++)
#pragma unroll
      for (int nt = 0; nt < NT; nt++)
        acc[mt][nt] = __builtin_amdgcn_mfma_f32_16x16x32_bf16(af[mt], bfr[nt], acc[mt][nt], 0, 0, 0);
  }

#pragma unroll
  for (int mt = 0; mt < MT; mt++)
#pragma unroll
    for (int nt = 0; nt < NT; nt++) {
      int r = Mblk + wm + mt * 16 + q * 4;
      int c = Nblk + wn + nt * 16 + fr;
#pragma unroll
      for (int i = 0; i < 4; i++) {
        size_t o = (size_t)(r + i) * N + c;
        float v = acc[mt][nt][i];
        if (res) v += res[o];
        C[o] = v;
      }
    }
}

// ---------------- fused depthwise conv(k=4)+bias+silu -> xc, and xp = xc @ Wx^T ----------------
// one wave per row t; 33 accumulators reduced by butterfly.
__global__ __launch_bounds__(256) void k_xpconv(const float* __restrict__ xz,
                                                const float* __restrict__ cw4,
                                                const float* __restrict__ cb,
                                                const float* __restrict__ Wx,
                                                float* __restrict__ xc,
                                                float* __restrict__ xp) {
  int lane = threadIdx.x & 63;
  int t = blockIdx.x * 4 + (threadIdx.x >> 6);
  float acc[33];
#pragma unroll
  for (int j = 0; j < 33; j++) acc[j] = 0.f;
  for (int k0 = 0; k0 < D_INNER; k0 += 64) {
    int k = k0 + lane;
    float4 w = *(const float4*)(cw4 + (size_t)k * 4);
    float wv[4] = {w.x, w.y, w.z, w.w};
    float v = cb[k];
#pragma unroll
    for (int jj = 0; jj < 4; jj++) {
      int ts = t - 3 + jj;                 // wave-uniform branch (t uniform per wave)
      if (ts >= 0) v += wv[jj] * xz[(size_t)ts * D_XZ + k];
    }
    float xcv = silu_f(v);
    xc[(size_t)t * D_INNER + k] = xcv;
#pragma unroll
    for (int j = 0; j < 33; j++) acc[j] += xcv * Wx[(size_t)j * D_INNER + k];
  }
#pragma unroll
  for (int j = 0; j < 33; j++) {
    float v = acc[j];
#pragma unroll
    for (int m = 32; m; m >>= 1) v += __shfl_xor(v, m, 64);
    if (lane == j) xp[(size_t)t * 33 + j] = v;
  }
}

// ---------------- scan phase 1: per-chunk scan with h0=0 + cumprod(dA) ----------------
__global__ __launch_bounds__(256) void k_scan1(const float* __restrict__ xp,
                                               const float* __restrict__ xc,
                                               const float* __restrict__ dtw,
                                               const float* __restrict__ dtb,
                                               const float* __restrict__ Alog,
                                               float* __restrict__ hend,
                                               float* __restrict__ Pp) {
  __shared__ float sxp[CLEN * 33];
  int c = blockIdx.x;
  int d = blockIdx.y * 256 + threadIdx.x;
  for (int i = threadIdx.x; i < CLEN * 33; i += 256) sxp[i] = xp[(size_t)c * CLEN * 33 + i];
  __syncthreads();
  float Av[16];
#pragma unroll
  for (int n = 0; n < 16; n++) Av[n] = -__expf(Alog[(size_t)d * 16 + n]);
  float w_ = dtw[d], b_ = dtb[d];
  float h[16], P[16];
#pragma unroll
  for (int n = 0; n < 16; n++) { h[n] = 0.f; P[n] = 1.f; }
  const float* xcc = xc + (size_t)(c * CLEN) * D_INNER + d;
  for (int tl = 0; tl < CLEN; tl++) {
    float dtr = sxp[tl * 33];
    float xv = xcc[(size_t)tl * D_INNER];
    float dt = softplus_f(dtr * w_ + b_);
    float sx = dt * xv;
#pragma unroll
    for (int n = 0; n < 16; n++) {
      float dA = __expf(dt * Av[n]);
      h[n] = dA * h[n] + sx * sxp[tl * 33 + 1 + n];
      P[n] *= dA;
    }
  }
  size_t o = ((size_t)c * D_INNER + d) * 16;
#pragma unroll
  for (int n = 0; n < 16; n++) { hend[o + n] = h[n]; Pp[o + n] = P[n]; }
}

// ---------------- scan combine: sequential over chunks, parallel over (d,n) ----------------
__global__ __launch_bounds__(256) void k_comb(const float* __restrict__ hend,
                                              const float* __restrict__ Pp,
                                              float* __restrict__ h0) {
  int i = blockIdx.x * 256 + threadIdx.x;
  float h = 0.f;
  for (int c = 0; c < NCHUNK; c++) {
    h0[(size_t)c * (D_INNER * 16) + i] = h;
    h = Pp[(size_t)c * (D_INNER * 16) + i] * h + hend[(size_t)c * (D_INNER * 16) + i];
  }
}

// ---------------- scan phase 2: rescan from h0, y-reduce, +D skip, *silu(z) ----------------
__global__ __launch_bounds__(256) void k_scan2(const float* __restrict__ xp,
                                               const float* __restrict__ xc,
                                               const float* __restrict__ xz,
                                               const float* __restrict__ dtw,
                                               const float* __restrict__ dtb,
                                               const float* __restrict__ Alog,
                                               const float* __restrict__ Dp,
                                               const float* __restrict__ h0,
                                               float* __restrict__ g) {
  __shared__ float sxp[CLEN * 33];
  int c = blockIdx.x;
  int d = blockIdx.y * 256 + threadIdx.x;
  for (int i = threadIdx.x; i < CLEN * 33; i += 256) sxp[i] = xp[(size_t)c * CLEN * 33 + i];
  __syncthreads();
  float Av[16];
#pragma unroll
  for (int n = 0; n < 16; n++) Av[n] = -__expf(Alog[(size_t)d * 16 + n]);
  float w_ = dtw[d], b_ = dtb[d], Dv = Dp[d];
  float h[16];
  size_t ho = ((size_t)c * D_INNER + d) * 16;
#pragma unroll
  for (int n = 0; n < 16; n++) h[n] = h0[ho + n];
  for (int tl = 0; tl < CLEN; tl++) {
    int t = c * CLEN + tl;
    float dtr = sxp[tl * 33];
    float xv = xc[(size_t)t * D_INNER + d];
    float dt = softplus_f(dtr * w_ + b_);
    float sx = dt * xv;
    float y = 0.f;
#pragma unroll
    for (int n = 0; n < 16; n++) {
      float dA = __expf(dt * Av[n]);
      h[n] = dA * h[n] + sx * sxp[tl * 33 + 1 + n];
      y += h[n] * sxp[tl * 33 + 17 + n];
    }
    float z = xz[(size_t)t * D_XZ + D_INNER + d];
    g[(size_t)t * D_INNER + d] = (y + xv * Dv) * silu_f(z);
  }
}

extern "C" void kernel_launch(void* const* d_in, const int* in_sizes, int n_in,
                              void* d_out, int out_size, void* d_ws, size_t ws_size,
                              hipStream_t stream) {
  const int*   idx     = (const int*)d_in[0];
  const float* embed   = (const float*)d_in[1];
  const float* norm_w  = (const float*)d_in[2];
  const float* W_in    = (const float*)d_in[3];
  const float* conv_w  = (const float*)d_in[4];
  const float* conv_b  = (const float*)d_in[5];
  const float* W_x     = (const float*)d_in[6];
  const float* dt_w    = (const float*)d_in[7];
  const float* dt_b    = (const float*)d_in[8];
  const float* A_log   = (const float*)d_in[9];
  const float* Dp      = (const float*)d_in[10];
  const float* out_w   = (const float*)d_in[11];
  const float* norm_fw = (const float*)d_in[12];
  float* out = (float*)d_out;

  float* x    = (float*)d_ws;           // 1024*768
  float* xz   = x    + 1024 * 768;      // 1024*3072
  float* xc   = xz   + 1024 * 3072;     // 1024*1536
  float* xp   = xc   + 1024 * 1536;     // 1024*33
  float* g    = xp   + 1024 * 33;       // 1024*1536
  float* hend = g    + 1024 * 1536;     // 32*1536*16
  float* Pp   = hend + NCHUNK * D_INNER * 16;
  float* h0b  = Pp   + NCHUNK * D_INNER * 16;
  float* rs   = h0b  + NCHUNK * D_INNER * 16;  // 1024

  k_gather<<<1024, 256, 0, stream>>>(embed, idx, x);

  for (int l = 0; l < 4; l++) {
    k_rowscale<<<256, 256, 0, stream>>>(x, rs);
    // xz = rmsnorm(x) @ W_in^T : M=1024 N=3072 K=768 (norm fused into staging)
    k_gemm<128, 128, true><<<dim3(8, 24), 256, 0, stream>>>(
        x, W_in + (size_t)l * D_XZ * D_MODEL, rs, norm_w + (size_t)l * D_MODEL,
        nullptr, xz, 1024, D_XZ, D_MODEL);
    k_xpconv<<<256, 256, 0, stream>>>(xz, conv_w + (size_t)l * D_INNER * 4,
                                      conv_b + (size_t)l * D_INNER,
                                      W_x + (size_t)l * 33 * D_INNER, xc, xp);
    k_scan1<<<dim3(NCHUNK, 6), 256, 0, stream>>>(xp, xc, dt_w + (size_t)l * D_INNER,
                                                 dt_b + (size_t)l * D_INNER,
                                                 A_log + (size_t)l * D_INNER * 16, hend, Pp);
    k_comb<<<(D_INNER * 16) / 256, 256, 0, stream>>>(hend, Pp, h0b);
    k_scan2<<<dim3(NCHUNK, 6), 256, 0, stream>>>(xp, xc, xz, dt_w + (size_t)l * D_INNER,
                                                 dt_b + (size_t)l * D_INNER,
                                                 A_log + (size_t)l * D_INNER * 16,
                                                 Dp + (size_t)l * D_INNER, h0b, g);
    // x = x + g @ out_w^T : M=1024 N=768 K=1536, 64x128 tile -> 96 blocks
    k_gemm<64, 128, false><<<dim3(16, 6), 256, 0, stream>>>(
        g, out_w + (size_t)l * D_MODEL * D_INNER, nullptr, nullptr,
        x, x, 1024, D_MODEL, D_INNER);
  }

  k_rowscale<<<256, 256, 0, stream>>>(x, rs);
  // logits = rmsnorm(x) @ embed^T : M=1024 N=32000 K=768
  k_gemm<128, 128, true><<<dim3(8, 250), 256, 0, stream>>>(
      x, embed, rs, norm_fw, nullptr, out, 1024, 32000, D_MODEL);
}

// Round 3
// 913.573 us; speedup vs baseline: 1.2825x; 1.2825x over previous
//
// Round 3: bf16 weights pre-converted once/call -> m97-style GEMM with
// global_load_lds(16B) both operands (zero staging VALU); XCD-contiguous
// tile mapping (each XCD reads 1/8 of B once); xpconv split-K 4 waves/row;
// embed converted after layer loop into dead pool space to bound ws usage.
#include <hip/hip_runtime.h>

#define D_MODEL 768
#define D_INNER 1536
#define D_XZ    3072
#define D_STATE 16
#define LSEQ    1024
#define NCHUNK  32
#define CLEN    32

typedef float  floatx4 __attribute__((ext_vector_type(4)));
typedef __bf16 bf16x2  __attribute__((ext_vector_type(2)));
typedef __bf16 bf16x8  __attribute__((ext_vector_type(8)));

__device__ __forceinline__ float softplus_f(float x) {
  float e = __expf(-fabsf(x));
  return fmaxf(x, 0.f) + __logf(1.f + e);
}
__device__ __forceinline__ float silu_f(float x) {
  return x / (1.f + __expf(-x));
}
__device__ __forceinline__ void gload_lds16(const void* g, void* l) {
  __builtin_amdgcn_global_load_lds(
      (const __attribute__((address_space(1))) void*)g,
      (__attribute__((address_space(3))) void*)l, 16, 0, 0);
}

// ---------------- fp32 -> bf16 bulk convert (8 elems/thread) ----------------
__global__ __launch_bounds__(256) void k_cvt(const float* __restrict__ src,
                                             __bf16* __restrict__ dst) {
  size_t i = ((size_t)blockIdx.x * 256 + threadIdx.x) * 8;
  float4 a = *(const float4*)(src + i);
  float4 b = *(const float4*)(src + i + 4);
  bf16x8 o;
  o[0] = (__bf16)a.x; o[1] = (__bf16)a.y; o[2] = (__bf16)a.z; o[3] = (__bf16)a.w;
  o[4] = (__bf16)b.x; o[5] = (__bf16)b.y; o[6] = (__bf16)b.z; o[7] = (__bf16)b.w;
  *(bf16x8*)(dst + i) = o;
}

// ---------------- embed gather ----------------
__global__ __launch_bounds__(256) void k_gather(const float* __restrict__ embed,
                                                const int* __restrict__ idx,
                                                float* __restrict__ x) {
  int t = blockIdx.x;
  int tok = idx[t];
  const float* src = embed + (size_t)tok * D_MODEL;
  float* dst = x + (size_t)t * D_MODEL;
  for (int c = threadIdx.x; c < D_MODEL; c += 256) dst[c] = src[c];
}

// ---------------- rmsnorm -> bf16 out (wave per row; lane = 6 float2 pairs) ----------------
__global__ __launch_bounds__(256) void k_rmsnorm_bf(const float* __restrict__ x,
                                                    const float* __restrict__ w,
                                                    __bf16* __restrict__ o) {
  int lane = threadIdx.x & 63;
  int row = blockIdx.x * 4 + (threadIdx.x >> 6);
  const float* xr = x + (size_t)row * D_MODEL;
  float2 v[6];
  float ss = 0.f;
#pragma unroll
  for (int i = 0; i < 6; i++) {
    v[i] = *(const float2*)(xr + lane * 2 + i * 128);
    ss += v[i].x * v[i].x + v[i].y * v[i].y;
  }
#pragma unroll
  for (int m = 32; m; m >>= 1) ss += __shfl_xor(ss, m, 64);
  float r = rsqrtf(ss * (1.f / 768.f) + 1e-5f);
  __bf16* orow = o + (size_t)row * D_MODEL;
#pragma unroll
  for (int i = 0; i < 6; i++) {
    float2 wv = *(const float2*)(w + lane * 2 + i * 128);
    bf16x2 p;
    p[0] = (__bf16)(v[i].x * r * wv.x);
    p[1] = (__bf16)(v[i].y * r * wv.y);
    *(bf16x2*)(orow + lane * 2 + i * 128) = p;
  }
}

// ---------------- bf16 NT GEMM, m97 structure ----------------
// C[m,n] = res?[m,n] + sum_k A[m,k]*B[n,k].  A: MxK bf16, B: NxK bf16, C fp32.
// TN=128 fixed. global_load_lds 16B staging, LDS stride 32 (layout mandated by
// lane-contiguous DMA). XCD-contiguous mapping: v=(id%8)*(grid/8)+id/8.
template <int TM>
__global__ __launch_bounds__(256) void k_gemm_bb(const __bf16* __restrict__ A,
                                                 const __bf16* __restrict__ B,
                                                 const float* res, float* __restrict__ C,
                                                 int M, int N, int K, int mTiles) {
  constexpr int MT = TM / 32;
  __shared__ __attribute__((aligned(16))) __bf16 As[TM * 32];
  __shared__ __attribute__((aligned(16))) __bf16 Bs[128 * 32];
  const int tid = threadIdx.x;
  const int lane = tid & 63, wave = tid >> 6;
  const int fr = lane & 15, q = lane >> 4, kq = q * 8;

  int id = blockIdx.x;
  int per = gridDim.x >> 3;
  int v = (id & 7) * per + (id >> 3);
  int nt = v / mTiles, mt_ = v % mTiles;
  const int Mblk = mt_ * TM, Nblk = nt * 128;

  const int wm = (wave & 1) * (TM / 2), wn = (wave >> 1) * 64;

  const int row_s = tid >> 2;          // 0..63
  const int col_s = (tid & 3) * 8;     // bf16 elems (16B chunk)
  const __bf16* Ag = A + (size_t)(Mblk + row_s) * K + col_s;
  const __bf16* Bg = B + (size_t)(Nblk + row_s) * K + col_s;
  __bf16* Asd = &As[tid * 8];
  __bf16* Bsd = &Bs[tid * 8];

  floatx4 acc[MT][4];
#pragma unroll
  for (int i = 0; i < MT; i++)
#pragma unroll
    for (int j = 0; j < 4; j++) {
      floatx4 z = {0.f, 0.f, 0.f, 0.f};
      acc[i][j] = z;
    }

  for (int k0 = 0; k0 < K; k0 += 32) {
    __syncthreads();
#pragma unroll
    for (int i = 0; i < TM / 64; i++)
      gload_lds16(Ag + (size_t)(64 * i) * K + k0, Asd + i * 2048);
#pragma unroll
    for (int i = 0; i < 2; i++)
      gload_lds16(Bg + (size_t)(64 * i) * K + k0, Bsd + i * 2048);
    __syncthreads();
    bf16x8 af[MT], bfr[4];
#pragma unroll
    for (int mt = 0; mt < MT; mt++) af[mt] = *(const bf16x8*)&As[(wm + mt * 16 + fr) * 32 + kq];
#pragma unroll
    for (int ntl = 0; ntl < 4; ntl++) bfr[ntl] = *(const bf16x8*)&Bs[(wn + ntl * 16 + fr) * 32 + kq];
#pragma unroll
    for (int mt = 0; mt < MT; mt++)
#pragma unroll
      for (int ntl = 0; ntl < 4; ntl++)
        acc[mt][ntl] = __builtin_amdgcn_mfma_f32_16x16x32_bf16(af[mt], bfr[ntl], acc[mt][ntl], 0, 0, 0);
  }

#pragma unroll
  for (int mt = 0; mt < MT; mt++)
#pragma unroll
    for (int ntl = 0; ntl < 4; ntl++) {
      int r = Mblk + wm + mt * 16 + q * 4;
      int c = Nblk + wn + ntl * 16 + fr;
#pragma unroll
      for (int i = 0; i < 4; i++) {
        size_t o = (size_t)(r + i) * N + c;
        float vv = acc[mt][ntl][i];
        if (res) vv += res[o];
        C[o] = vv;
      }
    }
}

// ---------------- fused conv(k=4)+bias+silu -> xc, xp = xc @ Wx^T ----------------
// one block per row t; 4 waves split K (384 each); LDS cross-wave reduce.
__global__ __launch_bounds__(256) void k_xpconv(const float* __restrict__ xz,
                                                const float* __restrict__ cw4,
                                                const float* __restrict__ cb,
                                                const float* __restrict__ Wx,
                                                float* __restrict__ xc,
                                                float* __restrict__ xp) {
  __shared__ float red[4][33];
  int t = blockIdx.x;
  int wave = threadIdx.x >> 6, lane = threadIdx.x & 63;
  float acc[33];
#pragma unroll
  for (int j = 0; j < 33; j++) acc[j] = 0.f;
  for (int ii = 0; ii < 6; ii++) {
    int k = wave * 384 + ii * 64 + lane;
    float4 w = *(const float4*)(cw4 + (size_t)k * 4);
    float wv[4] = {w.x, w.y, w.z, w.w};
    float vv = cb[k];
#pragma unroll
    for (int jj = 0; jj < 4; jj++) {
      int ts = t - 3 + jj;  // block-uniform branch
      if (ts >= 0) vv += wv[jj] * xz[(size_t)ts * D_XZ + k];
    }
    float xcv = silu_f(vv);
    xc[(size_t)t * D_INNER + k] = xcv;
#pragma unroll
    for (int j = 0; j < 33; j++) acc[j] += xcv * Wx[(size_t)j * D_INNER + k];
  }
#pragma unroll
  for (int j = 0; j < 33; j++) {
    float s = acc[j];
#pragma unroll
    for (int m = 32; m; m >>= 1) s += __shfl_xor(s, m, 64);
    if (lane == j) red[wave][j] = s;
  }
  __syncthreads();
  int j = threadIdx.x;
  if (j < 33) xp[(size_t)t * 33 + j] = red[0][j] + red[1][j] + red[2][j] + red[3][j];
}

// ---------------- scan phase 1 ----------------
__global__ __launch_bounds__(256) void k_scan1(const float* __restrict__ xp,
                                               const float* __restrict__ xc,
                                               const float* __restrict__ dtw,
                                               const float* __restrict__ dtb,
                                               const float* __restrict__ Alog,
                                               float* __restrict__ hend,
                                               float* __restrict__ Pp) {
  __shared__ float sxp[CLEN * 33];
  int c = blockIdx.x;
  int d = blockIdx.y * 256 + threadIdx.x;
  for (int i = threadIdx.x; i < CLEN * 33; i += 256) sxp[i] = xp[(size_t)c * CLEN * 33 + i];
  __syncthreads();
  float Av[16];
#pragma unroll
  for (int n = 0; n < 16; n++) Av[n] = -__expf(Alog[(size_t)d * 16 + n]);
  float w_ = dtw[d], b_ = dtb[d];
  float h[16], P[16];
#pragma unroll
  for (int n = 0; n < 16; n++) { h[n] = 0.f; P[n] = 1.f; }
  const float* xcc = xc + (size_t)(c * CLEN) * D_INNER + d;
  for (int tl = 0; tl < CLEN; tl++) {
    float dtr = sxp[tl * 33];
    float xv = xcc[(size_t)tl * D_INNER];
    float dt = softplus_f(dtr * w_ + b_);
    float sx = dt * xv;
#pragma unroll
    for (int n = 0; n < 16; n++) {
      float dA = __expf(dt * Av[n]);
      h[n] = dA * h[n] + sx * sxp[tl * 33 + 1 + n];
      P[n] *= dA;
    }
  }
  size_t o = ((size_t)c * D_INNER + d) * 16;
#pragma unroll
  for (int n = 0; n < 16; n++) { hend[o + n] = h[n]; Pp[o + n] = P[n]; }
}

// ---------------- scan combine ----------------
__global__ __launch_bounds__(256) void k_comb(const float* __restrict__ hend,
                                              const float* __restrict__ Pp,
                                              float* __restrict__ h0) {
  int i = blockIdx.x * 256 + threadIdx.x;
  float h = 0.f;
  for (int c = 0; c < NCHUNK; c++) {
    h0[(size_t)c * (D_INNER * 16) + i] = h;
    h = Pp[(size_t)c * (D_INNER * 16) + i] * h + hend[(size_t)c * (D_INNER * 16) + i];
  }
}

// ---------------- scan phase 2: rescan + y + D-skip + silu gate -> bf16 g ----------------
__global__ __launch_bounds__(256) void k_scan2(const float* __restrict__ xp,
                                               const float* __restrict__ xc,
                                               const float* __restrict__ xz,
                                               const float* __restrict__ dtw,
                                               const float* __restrict__ dtb,
                                               const float* __restrict__ Alog,
                                               const float* __restrict__ Dp,
                                               const float* __restrict__ h0,
                                               __bf16* __restrict__ g) {
  __shared__ float sxp[CLEN * 33];
  int c = blockIdx.x;
  int d = blockIdx.y * 256 + threadIdx.x;
  for (int i = threadIdx.x; i < CLEN * 33; i += 256) sxp[i] = xp[(size_t)c * CLEN * 33 + i];
  __syncthreads();
  float Av[16];
#pragma unroll
  for (int n = 0; n < 16; n++) Av[n] = -__expf(Alog[(size_t)d * 16 + n]);
  float w_ = dtw[d], b_ = dtb[d], Dv = Dp[d];
  float h[16];
  size_t ho = ((size_t)c * D_INNER + d) * 16;
#pragma unroll
  for (int n = 0; n < 16; n++) h[n] = h0[ho + n];
  for (int tl = 0; tl < CLEN; tl++) {
    int t = c * CLEN + tl;
    float dtr = sxp[tl * 33];
    float xv = xc[(size_t)t * D_INNER + d];
    float dt = softplus_f(dtr * w_ + b_);
    float sx = dt * xv;
    float y = 0.f;
#pragma unroll
    for (int n = 0; n < 16; n++) {
      float dA = __expf(dt * Av[n]);
      h[n] = dA * h[n] + sx * sxp[tl * 33 + 1 + n];
      y += h[n] * sxp[tl * 33 + 17 + n];
    }
    float z = xz[(size_t)t * D_XZ + D_INNER + d];
    g[(size_t)t * D_INNER + d] = (__bf16)((y + xv * Dv) * silu_f(z));
  }
}

extern "C" void kernel_launch(void* const* d_in, const int* in_sizes, int n_in,
                              void* d_out, int out_size, void* d_ws, size_t ws_size,
                              hipStream_t stream) {
  const int*   idx     = (const int*)d_in[0];
  const float* embed   = (const float*)d_in[1];
  const float* norm_w  = (const float*)d_in[2];
  const float* W_in    = (const float*)d_in[3];
  const float* conv_w  = (const float*)d_in[4];
  const float* conv_b  = (const float*)d_in[5];
  const float* W_x     = (const float*)d_in[6];
  const float* dt_w    = (const float*)d_in[7];
  const float* dt_b    = (const float*)d_in[8];
  const float* A_log   = (const float*)d_in[9];
  const float* Dp      = (const float*)d_in[10];
  const float* out_w   = (const float*)d_in[11];
  const float* norm_fw = (const float*)d_in[12];
  float* out = (float*)d_out;

  // ---- workspace layout (pool region re-used for bf16 embed at the end) ----
  float*  x    = (float*)d_ws;                     // 786432 f
  __bf16* xnb  = (__bf16*)(x + 786432);            // 786432 bf
  float*  xp   = (float*)(xnb + 786432);           // 33792 f
  float*  Pp   = xp + 33792;                       // 786432 f
  float*  h0b  = Pp + 786432;                      // 786432 f
  __bf16* gbf  = (__bf16*)(h0b + 786432);          // 1572864 bf
  __bf16* pool = gbf + 1572864;                    // pool: 52.8 MB
  __bf16* W_in_bf  = pool;                         // 9437184 bf
  __bf16* out_w_bf = pool + 9437184;               // 4718592 bf
  float*  xz   = (float*)(out_w_bf + 4718592);     // 3145728 f
  float*  xc   = xz + 3145728;                     // 1572864 f
  float*  hend = xc + 1572864;                     // 786432 f
  __bf16* emb_bf = pool;                           // 24576000 bf (aliases pool AFTER layers)

  // weight conversions (embed deferred until pool is dead)
  k_cvt<<<4608, 256, 0, stream>>>(W_in, W_in_bf);      // 9,437,184 elems
  k_cvt<<<2304, 256, 0, stream>>>(out_w, out_w_bf);    // 4,718,592 elems

  k_gather<<<1024, 256, 0, stream>>>(embed, idx, x);

  for (int l = 0; l < 4; l++) {
    k_rmsnorm_bf<<<256, 256, 0, stream>>>(x, norm_w + (size_t)l * D_MODEL, xnb);
    // xz = xn @ W_in^T : M=1024 N=3072 K=768 -> 24 n-tiles x 8 m-tiles
    k_gemm_bb<128><<<192, 256, 0, stream>>>(xnb, W_in_bf + (size_t)l * D_XZ * D_MODEL,
                                            nullptr, xz, 1024, D_XZ, D_MODEL, 8);
    k_xpconv<<<1024, 256, 0, stream>>>(xz, conv_w + (size_t)l * D_INNER * 4,
                                       conv_b + (size_t)l * D_INNER,
                                       W_x + (size_t)l * 33 * D_INNER, xc, xp);
    k_scan1<<<dim3(NCHUNK, 6), 256, 0, stream>>>(xp, xc, dt_w + (size_t)l * D_INNER,
                                                 dt_b + (size_t)l * D_INNER,
                                                 A_log + (size_t)l * D_INNER * 16, hend, Pp);
    k_comb<<<(D_INNER * 16) / 256, 256, 0, stream>>>(hend, Pp, h0b);
    k_scan2<<<dim3(NCHUNK, 6), 256, 0, stream>>>(xp, xc, xz, dt_w + (size_t)l * D_INNER,
                                                 dt_b + (size_t)l * D_INNER,
                                                 A_log + (size_t)l * D_INNER * 16,
                                                 Dp + (size_t)l * D_INNER, h0b, gbf);
    // x = x + g @ out_w^T : M=1024 N=768 K=1536 -> TM=64: 6 n-tiles x 16 m-tiles
    k_gemm_bb<64><<<96, 256, 0, stream>>>(gbf, out_w_bf + (size_t)l * D_MODEL * D_INNER,
                                          x, x, 1024, D_MODEL, D_INNER, 16);
  }

  // pool (W_in_bf/out_w_bf/xz/xc/hend) is dead now -> convert embed into it
  k_cvt<<<12000, 256, 0, stream>>>(embed, emb_bf);     // 24,576,000 elems
  k_rmsnorm_bf<<<256, 256, 0, stream>>>(x, norm_fw, xnb);
  // logits = xn @ embed^T : M=1024 N=32000 K=768 -> 250 n-tiles x 8 m-tiles
  k_gemm_bb<128><<<2000, 256, 0, stream>>>(xnb, emb_bf, nullptr, out,
                                           1024, 32000, D_MODEL, 8);
}